// Round 5
// baseline (31951.245 us; speedup 1.0000x reference)
//
#include <hip/hip_runtime.h>

#define Tn     512
#define Dn     64
#define Hn     512
#define BB     32              // batch rows per block -> 64 blocks
#define NB     (2048 / BB)     // 64 blocks
#define KSTEPS 20              // 640 / 32
#define SHS    516             // sh row stride (fp32)

typedef __attribute__((ext_vector_type(8))) short  short8;   // 8 bf16 (4 VGPRs)
typedef __attribute__((ext_vector_type(4))) float  floatx4;  // MFMA acc / native vec

__device__ __forceinline__ unsigned short f2bf(float f) {
  unsigned u = __float_as_uint(f);
  unsigned r = u + 0x7fffu + ((u >> 16) & 1u);
  return (unsigned short)(r >> 16);
}
__device__ __forceinline__ float frcp(float x) { return __builtin_amdgcn_rcpf(x); }
__device__ __forceinline__ float sigm(float x) { return frcp(1.f + __expf(-x)); }
__device__ __forceinline__ float tanhfast(float y) {
  float a = fabsf(y);
  float e = __expf(-2.f * a);
  float m = 1.f - 2.f * e * frcp(1.f + e);
  return copysignf(m, y);
}

// ---------------------------------------------------------------------------
// Prep: pack W_cat^T into per-wave-contiguous MFMA B-fragment order, bf16.
// flat = ((ks*8 + w)*12 + f)*64 + lane,  f = g*4+t (g: 0=r,1=z,2=n)
// col n = g*512 + w*64 + t*16 + (lane&15); k = ks*32 + (lane>>4)*8 + j
// Also zeroes the phase-lock counter.
// ---------------------------------------------------------------------------
__global__ __launch_bounds__(256) void cru_prep(
    const float* __restrict__ W_ih, const float* __restrict__ W_hh,
    short8* __restrict__ WB, unsigned int* __restrict__ ctr)
{
  int idx = blockIdx.x * 256 + threadIdx.x;
  if (idx == 0) *ctr = 0u;
  if (idx >= KSTEPS * 8 * 12 * 64) return;
  int lane = idx & 63;
  int rem  = idx >> 6;
  int f    = rem % 12; rem /= 12;
  int w    = rem & 7;
  int ks   = rem >> 3;
  int g = f >> 2, tt = f & 3;
  int n  = g * 512 + w * 64 + tt * 16 + (lane & 15);
  int k0 = ks * 32 + (lane >> 4) * 8;
  const float* src = (k0 < 128) ? (W_ih + (size_t)n * 128 + k0)
                                : (W_hh + (size_t)n * 512 + (k0 - 128));
  float4 x0 = ((const float4*)src)[0];
  float4 x1 = ((const float4*)src)[1];
  union { unsigned short us[8]; short8 v; } pk;
  pk.us[0] = f2bf(x0.x); pk.us[1] = f2bf(x0.y); pk.us[2] = f2bf(x0.z); pk.us[3] = f2bf(x0.w);
  pk.us[4] = f2bf(x1.x); pk.us[5] = f2bf(x1.y); pk.us[6] = f2bf(x1.z); pk.us[7] = f2bf(x1.w);
  WB[idx] = pk.v;
}

__device__ __forceinline__ void loadB(const short8* __restrict__ p, int ks, short8 B[12]) {
  const short8* q = p + (size_t)ks * 6144;   // 8*12*64 frags per ks
  #pragma unroll
  for (int f = 0; f < 12; ++f) B[f] = q[f * 64];
}

// ---------------------------------------------------------------------------
// Main: 64 blocks x 512 threads (8 waves). Block owns 32 batch rows (2 M-tiles).
// Per-step phase-lock barrier keeps all blocks walking the weight stream in
// phase (pure performance: promotes weight lines to L2-resident; results do
// not depend on it — relaxed atomics, bounded spin, monotone counter).
// ---------------------------------------------------------------------------
__global__ __launch_bounds__(512, 2) void cru_main(
    const float* __restrict__ values, const float* __restrict__ maskp,
    const float* __restrict__ tsp,
    const float* __restrict__ b_ih, const float* __restrict__ b_hh,
    const float* __restrict__ W_decay, const float* __restrict__ b_decay,
    const float* __restrict__ W_head, const float* __restrict__ b_head,
    const short8* __restrict__ WB,
    unsigned int* __restrict__ ctr,
    float* __restrict__ out)
{
  __shared__ float  sh[BB][SHS];               // fp32 master hidden state (66 KB)
  __shared__ short8 apk[2 * KSTEPS * 64];      // A frags, [mt][ks][lane] (40 KB)
  __shared__ float  sdt[BB];

  const int tid  = threadIdx.x;
  const int b0   = blockIdx.x * BB;
  const int w    = tid >> 6;
  const int lane = tid & 63;
  const int quad = lane >> 4;
  const int lc   = lane & 15;

  for (int i = tid; i < BB * SHS; i += 512) (&sh[0][0])[i] = 0.f;

  float bR[4], bZ[4], bIN[4], bHN[4], wdc[4], bdc[4];
  #pragma unroll
  for (int k = 0; k < 4; ++k) {
    int j = w * 64 + k * 16 + lc;
    bR[k]  = b_ih[j]        + b_hh[j];
    bZ[k]  = b_ih[j + 512]  + b_hh[j + 512];
    bIN[k] = b_ih[j + 1024];
    bHN[k] = b_hh[j + 1024];
    wdc[k] = W_decay[j];
    bdc[k] = b_decay[j];
  }

  const short8* WBw = WB + w * 768 + lane;     // wave-local fragment stream

  __syncthreads();

  short8 Bc[12], Bn[12];

  for (int t = 0; t < Tn; ++t) {
    // issue first two B-chunks early (fetch overlaps staging + barrier wait)
    loadB(WBw, 0, Bc);
    loadB(WBw, 1, Bn);

    // ---- stage A fragments: [x(bf16) | h(bf16)], both M-tiles ----
    for (int s = tid; s < 2 * KSTEPS * 64; s += 512) {
      int mt = s / (KSTEPS * 64);
      int r  = s % (KSTEPS * 64);
      int ks = r >> 6, ln = r & 63;
      int m  = mt * 16 + (ln & 15);
      int kg = ks * 32 + (ln >> 4) * 8;
      floatx4 x0, x1;
      if (ks < 4) {
        const floatx4* src = (kg < 64)
          ? (const floatx4*)(values + ((size_t)(b0 + m) * Tn + t) * Dn + kg)
          : (const floatx4*)(maskp  + ((size_t)(b0 + m) * Tn + t) * Dn + (kg - 64));
        x0 = __builtin_nontemporal_load(src);        // read-once stream: keep out of L2
        x1 = __builtin_nontemporal_load(src + 1);
      } else {
        const floatx4* src = (const floatx4*)&sh[m][kg - 128];
        x0 = src[0];
        x1 = src[1];
      }
      union { unsigned short us[8]; short8 v; } pk;
      pk.us[0] = f2bf(x0.x); pk.us[1] = f2bf(x0.y); pk.us[2] = f2bf(x0.z); pk.us[3] = f2bf(x0.w);
      pk.us[4] = f2bf(x1.x); pk.us[5] = f2bf(x1.y); pk.us[6] = f2bf(x1.z); pk.us[7] = f2bf(x1.w);
      apk[s] = pk.v;
    }
    if (tid < BB && t + 1 < Tn) {
      size_t rb = (size_t)(b0 + tid) * Tn + t;
      sdt[tid] = tsp[rb + 1] - tsp[rb];
    }
    __syncthreads();

    // ---- phase-lock barrier (performance-only; see header comment) ----
    if (tid == 0) {
      __hip_atomic_fetch_add(ctr, 1u, __ATOMIC_RELAXED, __HIP_MEMORY_SCOPE_AGENT);
      const unsigned target = (unsigned)NB * (unsigned)(t + 1);
      int guard = 1 << 20;
      while (__hip_atomic_load(ctr, __ATOMIC_RELAXED, __HIP_MEMORY_SCOPE_AGENT) < target
             && --guard) {
        __builtin_amdgcn_s_sleep(1);
      }
    }
    __syncthreads();

    floatx4 accR[4][2], accZ[4][2], accIN[4][2], accHN[4][2];
    #pragma unroll
    for (int k = 0; k < 4; ++k)
      #pragma unroll
      for (int mt = 0; mt < 2; ++mt) {
        accR[k][mt]  = (floatx4){0.f, 0.f, 0.f, 0.f};
        accZ[k][mt]  = (floatx4){0.f, 0.f, 0.f, 0.f};
        accIN[k][mt] = (floatx4){0.f, 0.f, 0.f, 0.f};
        accHN[k][mt] = (floatx4){0.f, 0.f, 0.f, 0.f};
      }

    // ---- K-loop: double-buffered B, 24 MFMAs per ks ----
    #pragma unroll
    for (int ks = 0; ks < KSTEPS; ++ks) {
      short8* Bu = (ks & 1) ? Bn : Bc;
      short8 A0 = apk[(0 * KSTEPS + ks) * 64 + lane];
      short8 A1 = apk[(1 * KSTEPS + ks) * 64 + lane];
      #pragma unroll
      for (int tt = 0; tt < 4; ++tt) {
        accR[tt][0] = __builtin_amdgcn_mfma_f32_16x16x32_bf16(A0, Bu[tt],     accR[tt][0], 0, 0, 0);
        accR[tt][1] = __builtin_amdgcn_mfma_f32_16x16x32_bf16(A1, Bu[tt],     accR[tt][1], 0, 0, 0);
        accZ[tt][0] = __builtin_amdgcn_mfma_f32_16x16x32_bf16(A0, Bu[4 + tt], accZ[tt][0], 0, 0, 0);
        accZ[tt][1] = __builtin_amdgcn_mfma_f32_16x16x32_bf16(A1, Bu[4 + tt], accZ[tt][1], 0, 0, 0);
        if (ks < 4) {
          accIN[tt][0] = __builtin_amdgcn_mfma_f32_16x16x32_bf16(A0, Bu[8 + tt], accIN[tt][0], 0, 0, 0);
          accIN[tt][1] = __builtin_amdgcn_mfma_f32_16x16x32_bf16(A1, Bu[8 + tt], accIN[tt][1], 0, 0, 0);
        } else {
          accHN[tt][0] = __builtin_amdgcn_mfma_f32_16x16x32_bf16(A0, Bu[8 + tt], accHN[tt][0], 0, 0, 0);
          accHN[tt][1] = __builtin_amdgcn_mfma_f32_16x16x32_bf16(A1, Bu[8 + tt], accHN[tt][1], 0, 0, 0);
        }
      }
      if (ks + 2 < KSTEPS) loadB(WBw, ks + 2, Bu);
    }

    // ---- epilogue: gates + update + next-step decay ----
    const bool last = (t == Tn - 1);
    #pragma unroll
    for (int k = 0; k < 4; ++k) {
      int j = w * 64 + k * 16 + lc;
      #pragma unroll
      for (int mt = 0; mt < 2; ++mt) {
        #pragma unroll
        for (int q = 0; q < 4; ++q) {
          int m = mt * 16 + quad * 4 + q;
          float r  = sigm(accR[k][mt][q] + bR[k]);
          float z  = sigm(accZ[k][mt][q] + bZ[k]);
          float nn = tanhfast(accIN[k][mt][q] + bIN[k] + r * (accHN[k][mt][q] + bHN[k]));
          float hnew = (1.f - z) * nn + z * sh[m][j];
          if (!last) {
            float pre = fmaf(sdt[m], wdc[k], bdc[k]);
            hnew *= frcp(1.f + __expf(pre));         // exp(-softplus(pre))
          }
          sh[m][j] = hnew;
        }
      }
    }
    __syncthreads();
  }

  // ---- head: out[b][nt] = h_T . W_head[nt] + b_head[nt] ----
  if (tid < BB * 8) {
    int b = tid >> 3, nt2 = tid & 7;
    float a = b_head[nt2];
    for (int k2 = 0; k2 < Hn; ++k2)
      a = fmaf(sh[b][k2], W_head[(size_t)nt2 * Hn + k2], a);
    out[(size_t)(b0 + b) * 8 + nt2] = a;
  }
}

extern "C" void kernel_launch(void* const* d_in, const int* in_sizes, int n_in,
                              void* d_out, int out_size, void* d_ws, size_t ws_size,
                              hipStream_t stream)
{
  const float* values  = (const float*)d_in[0];
  const float* mask    = (const float*)d_in[1];
  const float* tsp     = (const float*)d_in[2];
  const float* W_ih    = (const float*)d_in[3];
  const float* W_hh    = (const float*)d_in[4];
  const float* b_ih    = (const float*)d_in[5];
  const float* b_hh    = (const float*)d_in[6];
  const float* W_decay = (const float*)d_in[7];
  const float* b_decay = (const float*)d_in[8];
  const float* W_head  = (const float*)d_in[9];
  const float* b_head  = (const float*)d_in[10];
  float* out = (float*)d_out;

  short8* WB = (short8*)d_ws;                        // 1.97 MB of fragments
  int nfrag_total = KSTEPS * 8 * 12 * 64;
  unsigned int* ctr = (unsigned int*)((char*)d_ws + (((size_t)nfrag_total * 16 + 255) & ~(size_t)255));

  cru_prep<<<(nfrag_total + 255) / 256, 256, 0, stream>>>(W_ih, W_hh, WB, ctr);
  cru_main<<<NB, 512, 0, stream>>>(values, mask, tsp, b_ih, b_hh,
      W_decay, b_decay, W_head, b_head, WB, ctr, out);
}